// Round 3
// baseline (1145.197 us; speedup 1.0000x reference)
//
#include <hip/hip_runtime.h>
#include <hip/hip_bf16.h>

#define NU 100000
#define NM 20000
#define DD 64
#define RR 5
#define EE 400000
#define NE (RR * EE)            // 2,000,000 total edges
#define NNODE (NM + NU)         // 120,000 combined destination count

typedef __attribute__((ext_vector_type(8))) short bf16x8;
typedef __attribute__((ext_vector_type(4))) float f32x4;

static __device__ __forceinline__ short f2bf(float f) {
  return __builtin_bit_cast(short, __float2bfloat16(f));   // v_cvt_pk_bf16_f32 pairs
}
static __device__ __forceinline__ float bf2f(short s) {
  return __builtin_bit_cast(float, ((unsigned)(unsigned short)s) << 16);
}

static __device__ __forceinline__ bf16x8 cvt8(const float* __restrict__ p) {
  const float4 a = *(const float4*)p;
  const float4 b = *(const float4*)(p + 4);
  bf16x8 o;
  o[0] = f2bf(a.x); o[1] = f2bf(a.y); o[2] = f2bf(a.z); o[3] = f2bf(a.w);
  o[4] = f2bf(b.x); o[5] = f2bf(b.y); o[6] = f2bf(b.z); o[7] = f2bf(b.w);
  return o;
}

static __device__ __forceinline__ float sigm(float x) { return 1.f / (1.f + __expf(-x)); }
static __device__ __forceinline__ float gelu(float x) {
  return 0.5f * x * (1.f + erff(x * 0.70710678118654752f));
}

// ---------------------------------------------------------------------------
// Sort machinery: histogram -> scan(+cur) -> rank-assign
// ---------------------------------------------------------------------------
__global__ __launch_bounds__(256) void hist_k(const int* __restrict__ eu,
                                              const int* __restrict__ em,
                                              int* __restrict__ cnt) {
  const int i = (blockIdx.x * 256 + threadIdx.x) * 4;
  if (i < NE) {
    const int4 a = *(const int4*)(em + i);
    const int4 b = *(const int4*)(eu + i);
    atomicAdd(&cnt[a.x], 1); atomicAdd(&cnt[a.y], 1);
    atomicAdd(&cnt[a.z], 1); atomicAdd(&cnt[a.w], 1);
    atomicAdd(&cnt[NM + b.x], 1); atomicAdd(&cnt[NM + b.y], 1);
    atomicAdd(&cnt[NM + b.z], 1); atomicAdd(&cnt[NM + b.w], 1);
  }
}

__global__ __launch_bounds__(1024) void scan_k(const int* __restrict__ cnt,
                                               int* __restrict__ off,
                                               int* __restrict__ cur) {
  __shared__ int sums[1024];
  const int t = threadIdx.x;
  const int n = NNODE;
  const int ch = (n + 1023) >> 10;     // 118
  const int b0 = t * ch;
  int s = 0;
  for (int i = 0; i < ch; ++i) { int idx = b0 + i; if (idx < n) s += cnt[idx]; }
  sums[t] = s;
  __syncthreads();
  for (int d = 1; d < 1024; d <<= 1) {
    int x = (t >= d) ? sums[t - d] : 0;
    __syncthreads();
    sums[t] += x;
    __syncthreads();
  }
  int run = (t > 0) ? sums[t - 1] : 0;
  for (int i = 0; i < ch; ++i) {
    int idx = b0 + i;
    if (idx < n) { off[idx] = run; cur[idx] = run; run += cnt[idx]; }
  }
  if (t == 1023) off[n] = sums[1023];
}

__global__ __launch_bounds__(256) void rank_k(const int* __restrict__ eu,
                                              const int* __restrict__ em,
                                              int* __restrict__ cur,
                                              int* __restrict__ slot_m,
                                              int* __restrict__ slot_u) {
  const int i = (blockIdx.x * 256 + threadIdx.x) * 4;
  if (i < NE) {
    const int4 a = *(const int4*)(em + i);
    const int4 b = *(const int4*)(eu + i);
    int4 sm, su;
    sm.x = atomicAdd(&cur[a.x], 1);
    sm.y = atomicAdd(&cur[a.y], 1);
    sm.z = atomicAdd(&cur[a.z], 1);
    sm.w = atomicAdd(&cur[a.w], 1);
    su.x = atomicAdd(&cur[NM + b.x], 1) - NE;
    su.y = atomicAdd(&cur[NM + b.y], 1) - NE;
    su.z = atomicAdd(&cur[NM + b.z], 1) - NE;
    su.w = atomicAdd(&cur[NM + b.w], 1) - NE;
    *(int4*)(slot_m + i) = sm;
    *(int4*)(slot_u + i) = su;
  }
}

// ---------------------------------------------------------------------------
// Main fused MFMA kernel: per 16-edge tile compute both directions' messages
// and STORE them (bf16) at their destination-sorted slots.
// Column permutation: tile t, col c -> output dim d = 4*c + t.
// All gathers (edges/slots/cj/W-rows) issued BEFORE the MFMA chain.
// ---------------------------------------------------------------------------
__global__ __launch_bounds__(256) void gcmc_main_sorted(
    const int* __restrict__ edges_u, const int* __restrict__ edges_m,
    const float* __restrict__ rfeat,
    const float* __restrict__ W_user, const float* __restrict__ W_movie,
    const float* __restrict__ ps_u, const float* __restrict__ rs_u, const float* __restrict__ rw_u,
    const float* __restrict__ ps_m, const float* __restrict__ rs_m, const float* __restrict__ rw_m,
    const float* __restrict__ user_cj, const float* __restrict__ movie_cj,
    const int* __restrict__ slot_m, const int* __restrict__ slot_u,
    short* __restrict__ msg_m, short* __restrict__ msg_u)
{
  const int r    = blockIdx.y;
  const int lane = threadIdx.x & 63;
  const int wid  = threadIdx.x >> 6;
  const int c    = lane & 15;
  const int kr   = lane >> 4;
  const int wtile = blockIdx.x * 4 + wid;

  bf16x8 Bu[4][2], Bm[4][2], Bs[2];
#pragma unroll
  for (int t = 0; t < 4; ++t) {
#pragma unroll
    for (int s = 0; s < 2; ++s) {
      Bu[t][s] = cvt8(rw_u + ((size_t)r * DD + (4 * c + t)) * DD + s * 32 + kr * 8);
      Bm[t][s] = cvt8(rw_m + ((size_t)r * DD + (4 * c + t)) * DD + s * 32 + kr * 8);
    }
  }
#pragma unroll
  for (int s = 0; s < 2; ++s) {
    if (c < 4) {
      const float* v = (c == 0 ? rs_u : c == 1 ? ps_u : c == 2 ? rs_m : ps_m)
                       + r * DD + s * 32 + kr * 8;
      Bs[s] = cvt8(v);
    } else {
      bf16x8 z = {0, 0, 0, 0, 0, 0, 0, 0};
      Bs[s] = z;
    }
  }

  for (int tt = 0; tt < 8; ++tt) {
    const int tile = wtile * 8 + tt;
    if (tile >= (EE / 16)) break;
    const int e0 = tile * 16;

    // ---- A loads (independent of everything below) ----
    const float* arow = rfeat + ((size_t)r * EE + e0 + c) * DD + kr * 8;
    const bf16x8 A0 = cvt8(arow);
    const bf16x8 A1 = cvt8(arow + 32);

    // ---- edge / slot loads: this lane's 4 rows are consecutive -> int4 ----
    const int ebase = r * EE + e0 + kr * 4;
    const int4 eu4  = *(const int4*)(edges_u + ebase);
    const int4 em4  = *(const int4*)(edges_m + ebase);
    const int4 slm4 = *(const int4*)(slot_m + ebase);
    const int4 slu4 = *(const int4*)(slot_u + ebase);
    const int eus[4] = {eu4.x, eu4.y, eu4.z, eu4.w};
    const int ems[4] = {em4.x, em4.y, em4.z, em4.w};
    const int slm[4] = {slm4.x, slm4.y, slm4.z, slm4.w};
    const int slu[4] = {slu4.x, slu4.y, slu4.z, slu4.w};

    // ---- dependent gathers, all issued up-front ----
    float cju[4], cjm[4];
    float4 hu[4], hm[4];
#pragma unroll
    for (int q = 0; q < 4; ++q) {
      cju[q] = user_cj[eus[q]];
      cjm[q] = movie_cj[ems[q]];
      hu[q]  = *(const float4*)(W_user  + ((size_t)r * NU + eus[q]) * DD + 4 * c);
      hm[q]  = *(const float4*)(W_movie + ((size_t)r * NM + ems[q]) * DD + 4 * c);
    }

    // ---- MFMA ----
    f32x4 z4 = {0.f, 0.f, 0.f, 0.f};
    f32x4 Cu[4], Cm[4], Cs;
#pragma unroll
    for (int t = 0; t < 4; ++t) { Cu[t] = z4; Cm[t] = z4; }
    Cs = z4;
#pragma unroll
    for (int t = 0; t < 4; ++t) {
      Cu[t] = __builtin_amdgcn_mfma_f32_16x16x32_bf16(A0, Bu[t][0], Cu[t], 0, 0, 0);
      Cu[t] = __builtin_amdgcn_mfma_f32_16x16x32_bf16(A1, Bu[t][1], Cu[t], 0, 0, 0);
      Cm[t] = __builtin_amdgcn_mfma_f32_16x16x32_bf16(A0, Bm[t][0], Cm[t], 0, 0, 0);
      Cm[t] = __builtin_amdgcn_mfma_f32_16x16x32_bf16(A1, Bm[t][1], Cm[t], 0, 0, 0);
    }
    Cs = __builtin_amdgcn_mfma_f32_16x16x32_bf16(A0, Bs[0], Cs, 0, 0, 0);
    Cs = __builtin_amdgcn_mfma_f32_16x16x32_bf16(A1, Bs[1], Cs, 0, 0, 0);

    // ---- combine + store ----
#pragma unroll
    for (int q = 0; q < 4; ++q) {
      const int src = (lane & 48);
      const float su = __shfl(Cs[q], src);
      const float pu = __shfl(Cs[q], src | 1);
      const float sm = __shfl(Cs[q], src | 2);
      const float pm = __shfl(Cs[q], src | 3);
      const float sgu = sigm(su), pau = sigm(pu);
      const float sgm_ = sigm(sm), pam = sigm(pm);

      short4 vm, vu;
      vm.x = f2bf((hu[q].x * pau + Cu[0][q] * sgu) * cju[q]);
      vm.y = f2bf((hu[q].y * pau + Cu[1][q] * sgu) * cju[q]);
      vm.z = f2bf((hu[q].z * pau + Cu[2][q] * sgu) * cju[q]);
      vm.w = f2bf((hu[q].w * pau + Cu[3][q] * sgu) * cju[q]);
      vu.x = f2bf((hm[q].x * pam + Cm[0][q] * sgm_) * cjm[q]);
      vu.y = f2bf((hm[q].y * pam + Cm[1][q] * sgm_) * cjm[q]);
      vu.z = f2bf((hm[q].z * pam + Cm[2][q] * sgm_) * cjm[q]);
      vu.w = f2bf((hm[q].w * pam + Cm[3][q] * sgm_) * cjm[q]);

      *(short4*)(msg_m + ((size_t)slm[q] << 6) + 4 * c) = vm;
      *(short4*)(msg_u + ((size_t)slu[q] << 6) + 4 * c) = vu;
    }
  }
}

// ---------------------------------------------------------------------------
// Gather-reduce: one wave per destination node; sum its contiguous segment.
// 2-deep unrolled so two loads are in flight per wave.
// ---------------------------------------------------------------------------
__global__ __launch_bounds__(256) void gather_k(const int* __restrict__ off,
                                                const short* __restrict__ msg_m,
                                                const short* __restrict__ msg_u,
                                                float* __restrict__ out)
{
  const int w    = blockIdx.x * 4 + (threadIdx.x >> 6);
  const int lane = threadIdx.x & 63;
  const int grp  = lane >> 4;
  const int cc   = lane & 15;

  const bool isM = (w < NM);
  const int s0 = off[w]     - (isM ? 0 : NE);
  const int e0 = off[w + 1] - (isM ? 0 : NE);
  const short* msg = isM ? msg_m : msg_u;
  float* dst = isM ? (out + (size_t)NU * DD + (size_t)w * DD)
                   : (out + (size_t)(w - NM) * DD);

  float4 a0 = {0.f, 0.f, 0.f, 0.f};
  float4 a1 = {0.f, 0.f, 0.f, 0.f};
  int k = s0 + grp;
  for (; k + 4 < e0; k += 8) {
    const short4 v0 = *(const short4*)(msg + ((size_t)k << 6) + 4 * cc);
    const short4 v1 = *(const short4*)(msg + ((size_t)(k + 4) << 6) + 4 * cc);
    a0.x += bf2f(v0.x); a0.y += bf2f(v0.y); a0.z += bf2f(v0.z); a0.w += bf2f(v0.w);
    a1.x += bf2f(v1.x); a1.y += bf2f(v1.y); a1.z += bf2f(v1.z); a1.w += bf2f(v1.w);
  }
  if (k < e0) {
    const short4 v0 = *(const short4*)(msg + ((size_t)k << 6) + 4 * cc);
    a0.x += bf2f(v0.x); a0.y += bf2f(v0.y); a0.z += bf2f(v0.z); a0.w += bf2f(v0.w);
  }
  a0.x += a1.x; a0.y += a1.y; a0.z += a1.z; a0.w += a1.w;

  a0.x += __shfl_xor(a0.x, 16); a0.y += __shfl_xor(a0.y, 16);
  a0.z += __shfl_xor(a0.z, 16); a0.w += __shfl_xor(a0.w, 16);
  a0.x += __shfl_xor(a0.x, 32); a0.y += __shfl_xor(a0.y, 32);
  a0.z += __shfl_xor(a0.z, 32); a0.w += __shfl_xor(a0.w, 32);
  if (grp == 0) *(float4*)(dst + 4 * cc) = a0;
}

// ---------------------------------------------------------------------------
// FC kernel (in-place on d_out): row -> gelu(row*ci) @ W.T + b, 16 rows/wave.
// ---------------------------------------------------------------------------
__global__ __launch_bounds__(256) void gcmc_fc(
    float* __restrict__ out,
    const float* __restrict__ user_ci, const float* __restrict__ movie_ci,
    const float* __restrict__ ufc_w, const float* __restrict__ ufc_b,
    const float* __restrict__ ifc_w, const float* __restrict__ ifc_b)
{
  const int wt   = blockIdx.x * 4 + (threadIdx.x >> 6);
  const int lane = threadIdx.x & 63;
  const int c    = lane & 15;
  const int kr   = lane >> 4;
  const bool isU = wt < (NU / 16);
  float* base        = isU ? out : out + (size_t)NU * DD;
  const float* ci    = isU ? user_ci : movie_ci;
  const float* W     = isU ? ufc_w : ifc_w;
  const float* bias  = isU ? ufc_b : ifc_b;
  const int row0 = (isU ? wt : wt - (NU / 16)) * 16;

  bf16x8 B[4][2];
#pragma unroll
  for (int t = 0; t < 4; ++t)
#pragma unroll
    for (int s = 0; s < 2; ++s)
      B[t][s] = cvt8(W + (size_t)(4 * c + t) * DD + s * 32 + kr * 8);

  const float civ = ci[row0 + c];
  const float* arow = base + (size_t)(row0 + c) * DD + kr * 8;

  bf16x8 A0, A1;
  {
    const float4 a = *(const float4*)arow;
    const float4 b = *(const float4*)(arow + 4);
    const float4 a2 = *(const float4*)(arow + 32);
    const float4 b2 = *(const float4*)(arow + 36);
    A0[0] = f2bf(gelu(a.x * civ));  A0[1] = f2bf(gelu(a.y * civ));
    A0[2] = f2bf(gelu(a.z * civ));  A0[3] = f2bf(gelu(a.w * civ));
    A0[4] = f2bf(gelu(b.x * civ));  A0[5] = f2bf(gelu(b.y * civ));
    A0[6] = f2bf(gelu(b.z * civ));  A0[7] = f2bf(gelu(b.w * civ));
    A1[0] = f2bf(gelu(a2.x * civ)); A1[1] = f2bf(gelu(a2.y * civ));
    A1[2] = f2bf(gelu(a2.z * civ)); A1[3] = f2bf(gelu(a2.w * civ));
    A1[4] = f2bf(gelu(b2.x * civ)); A1[5] = f2bf(gelu(b2.y * civ));
    A1[6] = f2bf(gelu(b2.z * civ)); A1[7] = f2bf(gelu(b2.w * civ));
  }

  f32x4 z4 = {0.f, 0.f, 0.f, 0.f};
  f32x4 C[4];
#pragma unroll
  for (int t = 0; t < 4; ++t) {
    C[t] = z4;
    C[t] = __builtin_amdgcn_mfma_f32_16x16x32_bf16(A0, B[t][0], C[t], 0, 0, 0);
    C[t] = __builtin_amdgcn_mfma_f32_16x16x32_bf16(A1, B[t][1], C[t], 0, 0, 0);
  }

  const float4 b4 = *(const float4*)(bias + 4 * c);
#pragma unroll
  for (int q = 0; q < 4; ++q) {
    const int row = row0 + kr * 4 + q;
    float4 o;
    o.x = C[0][q] + b4.x; o.y = C[1][q] + b4.y;
    o.z = C[2][q] + b4.z; o.w = C[3][q] + b4.w;
    *(float4*)(base + (size_t)row * DD + 4 * c) = o;
  }
}

extern "C" void kernel_launch(void* const* d_in, const int* in_sizes, int n_in,
                              void* d_out, int out_size, void* d_ws, size_t ws_size,
                              hipStream_t stream) {
  const int*   edges_u  = (const int*)  d_in[0];
  const int*   edges_m  = (const int*)  d_in[1];
  const float* rfeat    = (const float*)d_in[2];
  const float* W_user   = (const float*)d_in[3];
  const float* W_movie  = (const float*)d_in[4];
  const float* ps_u     = (const float*)d_in[5];
  const float* rs_u     = (const float*)d_in[6];
  const float* rw_u     = (const float*)d_in[7];
  const float* ps_m     = (const float*)d_in[8];
  const float* rs_m     = (const float*)d_in[9];
  const float* rw_m     = (const float*)d_in[10];
  const float* user_cj  = (const float*)d_in[11];
  const float* user_ci  = (const float*)d_in[12];
  const float* movie_cj = (const float*)d_in[13];
  const float* movie_ci = (const float*)d_in[14];
  const float* ufc_w    = (const float*)d_in[15];
  const float* ufc_b    = (const float*)d_in[16];
  const float* ifc_w    = (const float*)d_in[17];
  const float* ifc_b    = (const float*)d_in[18];

  float* out = (float*)d_out;

  // ---- workspace layout ----
  char* ws = (char*)d_ws;
  size_t o = 0;
  auto alloc = [&](size_t bytes) { char* p = ws + o; o += (bytes + 255) & ~(size_t)255; return p; };
  int*   cnt    = (int*)  alloc(sizeof(int) * NNODE);
  int*   off    = (int*)  alloc(sizeof(int) * (NNODE + 1));
  int*   cur    = (int*)  alloc(sizeof(int) * NNODE);
  int*   slot_m = (int*)  alloc(sizeof(int) * NE);
  int*   slot_u = (int*)  alloc(sizeof(int) * NE);
  short* msg_m  = (short*)alloc(sizeof(short) * (size_t)NE * DD);
  short* msg_u  = (short*)alloc(sizeof(short) * (size_t)NE * DD);
  (void)ws_size;

  hipMemsetAsync(cnt, 0, sizeof(int) * NNODE, stream);
  hist_k<<<(NE / 4 + 255) / 256, 256, 0, stream>>>(edges_u, edges_m, cnt);
  scan_k<<<1, 1024, 0, stream>>>(cnt, off, cur);
  rank_k<<<(NE / 4 + 255) / 256, 256, 0, stream>>>(edges_u, edges_m, cur, slot_m, slot_u);

  dim3 g1((EE / 16 + 31) / 32, RR);
  gcmc_main_sorted<<<g1, 256, 0, stream>>>(edges_u, edges_m, rfeat, W_user, W_movie,
                                           ps_u, rs_u, rw_u, ps_m, rs_m, rw_m,
                                           user_cj, movie_cj, slot_m, slot_u,
                                           msg_m, msg_u);

  gather_k<<<NNODE / 4, 256, 0, stream>>>(off, msg_m, msg_u, out);

  gcmc_fc<<<(NNODE / 16) / 4, 256, 0, stream>>>(out, user_ci, movie_ci,
                                                ufc_w, ufc_b, ifc_w, ifc_b);
}

// Round 4
// 1011.172 us; speedup vs baseline: 1.1325x; 1.1325x over previous
//
#include <hip/hip_runtime.h>
#include <hip/hip_bf16.h>

#define NU 100000
#define NM 20000
#define DD 64
#define RR 5
#define EE 400000
#define NE (RR * EE)            // 2,000,000 edges per direction
#define NNODE (NM + NU)         // 120,000 destination bins (movies first)

typedef __attribute__((ext_vector_type(8))) short bf16x8;
typedef __attribute__((ext_vector_type(4))) float f32x4;

static __device__ __forceinline__ short f2bf(float f) {
  return __builtin_bit_cast(short, __float2bfloat16(f));
}
static __device__ __forceinline__ float bf2f(short s) {
  return __builtin_bit_cast(float, ((unsigned)(unsigned short)s) << 16);
}

static __device__ __forceinline__ bf16x8 cvt8(const float* __restrict__ p) {
  const float4 a = *(const float4*)p;
  const float4 b = *(const float4*)(p + 4);
  bf16x8 o;
  o[0] = f2bf(a.x); o[1] = f2bf(a.y); o[2] = f2bf(a.z); o[3] = f2bf(a.w);
  o[4] = f2bf(b.x); o[5] = f2bf(b.y); o[6] = f2bf(b.z); o[7] = f2bf(b.w);
  return o;
}

static __device__ __forceinline__ void acc4(float4& a, const short4 v) {
  a.x += bf2f(v.x); a.y += bf2f(v.y); a.z += bf2f(v.z); a.w += bf2f(v.w);
}

static __device__ __forceinline__ float sigm(float x) { return 1.f / (1.f + __expf(-x)); }
static __device__ __forceinline__ float gelu(float x) {
  return 0.5f * x * (1.f + erff(x * 0.70710678118654752f));
}

// ---------------------------------------------------------------------------
// rank0: ONE atomic pass. cnt (zeroed) -> per-edge rank within destination,
// and cnt ends up holding the per-node degree (input to scanoff).
// ---------------------------------------------------------------------------
__global__ __launch_bounds__(256) void rank0_k(const int* __restrict__ eu,
                                               const int* __restrict__ em,
                                               int* __restrict__ cnt,
                                               int* __restrict__ rank_m,
                                               int* __restrict__ rank_u) {
  const int i = (blockIdx.x * 256 + threadIdx.x) * 4;
  if (i < NE) {
    const int4 a = *(const int4*)(em + i);
    const int4 b = *(const int4*)(eu + i);
    int4 rm, ru;
    rm.x = atomicAdd(&cnt[a.x], 1);
    rm.y = atomicAdd(&cnt[a.y], 1);
    rm.z = atomicAdd(&cnt[a.z], 1);
    rm.w = atomicAdd(&cnt[a.w], 1);
    ru.x = atomicAdd(&cnt[NM + b.x], 1);
    ru.y = atomicAdd(&cnt[NM + b.y], 1);
    ru.z = atomicAdd(&cnt[NM + b.z], 1);
    ru.w = atomicAdd(&cnt[NM + b.w], 1);
    *(int4*)(rank_m + i) = rm;
    *(int4*)(rank_u + i) = ru;
  }
}

__global__ __launch_bounds__(1024) void scanoff_k(const int* __restrict__ cnt,
                                                  int* __restrict__ off) {
  __shared__ int sums[1024];
  const int t = threadIdx.x;
  const int ch = (NNODE + 1023) >> 10;    // 118
  const int b0 = t * ch;
  int s = 0;
  for (int i = 0; i < ch; ++i) { int idx = b0 + i; if (idx < NNODE) s += cnt[idx]; }
  sums[t] = s;
  __syncthreads();
  for (int d = 1; d < 1024; d <<= 1) {
    int x = (t >= d) ? sums[t - d] : 0;
    __syncthreads();
    sums[t] += x;
    __syncthreads();
  }
  int run = (t > 0) ? sums[t - 1] : 0;
  for (int i = 0; i < ch; ++i) {
    int idx = b0 + i;
    if (idx < NNODE) { off[idx] = run; run += cnt[idx]; }
  }
  if (t == 1023) off[NNODE] = sums[1023];
}

// ---------------------------------------------------------------------------
// Main fused MFMA kernel, ONE relation per dispatch. Computes both directions'
// messages for 16-edge tiles and stores them (bf16) at slot = off[dst]+rank.
// Column permutation: tile t, col c -> output dim d = 4*c + t.
// ---------------------------------------------------------------------------
__global__ __launch_bounds__(256) void gcmc_main_sorted(
    const int r,
    const int* __restrict__ edges_u, const int* __restrict__ edges_m,
    const float* __restrict__ rfeat,
    const float* __restrict__ W_user, const float* __restrict__ W_movie,
    const float* __restrict__ ps_u, const float* __restrict__ rs_u, const float* __restrict__ rw_u,
    const float* __restrict__ ps_m, const float* __restrict__ rs_m, const float* __restrict__ rw_m,
    const float* __restrict__ user_cj, const float* __restrict__ movie_cj,
    const int* __restrict__ rank_m, const int* __restrict__ rank_u,
    const int* __restrict__ off,
    short* __restrict__ msg)
{
  const int lane = threadIdx.x & 63;
  const int wid  = threadIdx.x >> 6;
  const int c    = lane & 15;
  const int kr   = lane >> 4;
  const int wtile = blockIdx.x * 4 + wid;

  bf16x8 Bu[4][2], Bm[4][2], Bs[2];
#pragma unroll
  for (int t = 0; t < 4; ++t) {
#pragma unroll
    for (int s = 0; s < 2; ++s) {
      Bu[t][s] = cvt8(rw_u + ((size_t)r * DD + (4 * c + t)) * DD + s * 32 + kr * 8);
      Bm[t][s] = cvt8(rw_m + ((size_t)r * DD + (4 * c + t)) * DD + s * 32 + kr * 8);
    }
  }
#pragma unroll
  for (int s = 0; s < 2; ++s) {
    if (c < 4) {
      const float* v = (c == 0 ? rs_u : c == 1 ? ps_u : c == 2 ? rs_m : ps_m)
                       + r * DD + s * 32 + kr * 8;
      Bs[s] = cvt8(v);
    } else {
      bf16x8 z = {0, 0, 0, 0, 0, 0, 0, 0};
      Bs[s] = z;
    }
  }

  for (int tt = 0; tt < 8; ++tt) {
    const int tile = wtile * 8 + tt;
    if (tile >= (EE / 16)) break;
    const int e0 = tile * 16;

    // ---- A loads ----
    const float* arow = rfeat + ((size_t)r * EE + e0 + c) * DD + kr * 8;
    const bf16x8 A0 = cvt8(arow);
    const bf16x8 A1 = cvt8(arow + 32);

    // ---- edge / rank loads: this lane's 4 rows are consecutive -> int4 ----
    const int ebase = r * EE + e0 + kr * 4;
    const int4 eu4  = *(const int4*)(edges_u + ebase);
    const int4 em4  = *(const int4*)(edges_m + ebase);
    const int4 rm4  = *(const int4*)(rank_m + ebase);
    const int4 ru4  = *(const int4*)(rank_u + ebase);
    const int eus[4] = {eu4.x, eu4.y, eu4.z, eu4.w};
    const int ems[4] = {em4.x, em4.y, em4.z, em4.w};
    const int rms[4] = {rm4.x, rm4.y, rm4.z, rm4.w};
    const int rus[4] = {ru4.x, ru4.y, ru4.z, ru4.w};

    // ---- dependent gathers, all issued up-front ----
    int slm[4], slu[4];
    float cju[4], cjm[4];
    float4 hu[4], hm[4];
#pragma unroll
    for (int q = 0; q < 4; ++q) {
      slm[q] = off[ems[q]] + rms[q];
      slu[q] = off[NM + eus[q]] + rus[q];
      cju[q] = user_cj[eus[q]];
      cjm[q] = movie_cj[ems[q]];
      hu[q]  = *(const float4*)(W_user  + ((size_t)r * NU + eus[q]) * DD + 4 * c);
      hm[q]  = *(const float4*)(W_movie + ((size_t)r * NM + ems[q]) * DD + 4 * c);
    }

    // ---- MFMA ----
    f32x4 z4 = {0.f, 0.f, 0.f, 0.f};
    f32x4 Cu[4], Cm[4], Cs;
#pragma unroll
    for (int t = 0; t < 4; ++t) { Cu[t] = z4; Cm[t] = z4; }
    Cs = z4;
#pragma unroll
    for (int t = 0; t < 4; ++t) {
      Cu[t] = __builtin_amdgcn_mfma_f32_16x16x32_bf16(A0, Bu[t][0], Cu[t], 0, 0, 0);
      Cu[t] = __builtin_amdgcn_mfma_f32_16x16x32_bf16(A1, Bu[t][1], Cu[t], 0, 0, 0);
      Cm[t] = __builtin_amdgcn_mfma_f32_16x16x32_bf16(A0, Bm[t][0], Cm[t], 0, 0, 0);
      Cm[t] = __builtin_amdgcn_mfma_f32_16x16x32_bf16(A1, Bm[t][1], Cm[t], 0, 0, 0);
    }
    Cs = __builtin_amdgcn_mfma_f32_16x16x32_bf16(A0, Bs[0], Cs, 0, 0, 0);
    Cs = __builtin_amdgcn_mfma_f32_16x16x32_bf16(A1, Bs[1], Cs, 0, 0, 0);

    // ---- combine + store ----
#pragma unroll
    for (int q = 0; q < 4; ++q) {
      const int src = (lane & 48);
      const float su = __shfl(Cs[q], src);
      const float pu = __shfl(Cs[q], src | 1);
      const float sm = __shfl(Cs[q], src | 2);
      const float pm = __shfl(Cs[q], src | 3);
      const float sgu = sigm(su), pau = sigm(pu);
      const float sgm_ = sigm(sm), pam = sigm(pm);

      short4 vm, vu;
      vm.x = f2bf((hu[q].x * pau + Cu[0][q] * sgu) * cju[q]);
      vm.y = f2bf((hu[q].y * pau + Cu[1][q] * sgu) * cju[q]);
      vm.z = f2bf((hu[q].z * pau + Cu[2][q] * sgu) * cju[q]);
      vm.w = f2bf((hu[q].w * pau + Cu[3][q] * sgu) * cju[q]);
      vu.x = f2bf((hm[q].x * pam + Cm[0][q] * sgm_) * cjm[q]);
      vu.y = f2bf((hm[q].y * pam + Cm[1][q] * sgm_) * cjm[q]);
      vu.z = f2bf((hm[q].z * pam + Cm[2][q] * sgm_) * cjm[q]);
      vu.w = f2bf((hm[q].w * pam + Cm[3][q] * sgm_) * cjm[q]);

      *(short4*)(msg + ((size_t)slm[q] << 6) + 4 * c) = vm;
      *(short4*)(msg + ((size_t)slu[q] << 6) + 4 * c) = vu;
    }
  }
}

// ---------------------------------------------------------------------------
// Gather-reduce, movies: one wave per movie (avg 100 rows), 4 groups x 4-deep.
// ---------------------------------------------------------------------------
__global__ __launch_bounds__(256) void gather_m_k(const int* __restrict__ off,
                                                  const short* __restrict__ msg,
                                                  float* __restrict__ out)
{
  const int w    = blockIdx.x * 4 + (threadIdx.x >> 6);   // movie id
  const int lane = threadIdx.x & 63;
  const int grp  = lane >> 4;
  const int cc   = lane & 15;

  const int s0 = off[w];
  const int e1 = off[w + 1];

  float4 a0 = {0,0,0,0}, a1 = {0,0,0,0}, a2 = {0,0,0,0}, a3 = {0,0,0,0};
  int k = s0 + grp;
  for (; k + 12 < e1; k += 16) {
    const short4 v0 = *(const short4*)(msg + ((size_t)k << 6) + 4 * cc);
    const short4 v1 = *(const short4*)(msg + ((size_t)(k + 4) << 6) + 4 * cc);
    const short4 v2 = *(const short4*)(msg + ((size_t)(k + 8) << 6) + 4 * cc);
    const short4 v3 = *(const short4*)(msg + ((size_t)(k + 12) << 6) + 4 * cc);
    acc4(a0, v0); acc4(a1, v1); acc4(a2, v2); acc4(a3, v3);
  }
  for (; k < e1; k += 4) {
    const short4 v0 = *(const short4*)(msg + ((size_t)k << 6) + 4 * cc);
    acc4(a0, v0);
  }
  a0.x += a1.x + a2.x + a3.x; a0.y += a1.y + a2.y + a3.y;
  a0.z += a1.z + a2.z + a3.z; a0.w += a1.w + a2.w + a3.w;

  a0.x += __shfl_xor(a0.x, 16); a0.y += __shfl_xor(a0.y, 16);
  a0.z += __shfl_xor(a0.z, 16); a0.w += __shfl_xor(a0.w, 16);
  a0.x += __shfl_xor(a0.x, 32); a0.y += __shfl_xor(a0.y, 32);
  a0.z += __shfl_xor(a0.z, 32); a0.w += __shfl_xor(a0.w, 32);
  if (grp == 0) *(float4*)(out + (size_t)NU * DD + (size_t)w * DD + 4 * cc) = a0;
}

// ---------------------------------------------------------------------------
// Gather-reduce, users: 16 lanes per user (avg 20 rows), 4 users/wave, 4-deep.
// ---------------------------------------------------------------------------
__global__ __launch_bounds__(256) void gather_u_k(const int* __restrict__ off,
                                                  const short* __restrict__ msg,
                                                  float* __restrict__ out)
{
  const int u  = blockIdx.x * 16 + (threadIdx.x >> 4);    // user id
  const int cc = threadIdx.x & 15;

  const int s0 = off[NM + u];
  const int e1 = off[NM + u + 1];

  float4 a0 = {0,0,0,0}, a1 = {0,0,0,0}, a2 = {0,0,0,0}, a3 = {0,0,0,0};
  int k = s0;
  for (; k + 3 < e1; k += 4) {
    const short4 v0 = *(const short4*)(msg + ((size_t)k << 6) + 4 * cc);
    const short4 v1 = *(const short4*)(msg + ((size_t)(k + 1) << 6) + 4 * cc);
    const short4 v2 = *(const short4*)(msg + ((size_t)(k + 2) << 6) + 4 * cc);
    const short4 v3 = *(const short4*)(msg + ((size_t)(k + 3) << 6) + 4 * cc);
    acc4(a0, v0); acc4(a1, v1); acc4(a2, v2); acc4(a3, v3);
  }
  for (; k < e1; ++k) {
    const short4 v0 = *(const short4*)(msg + ((size_t)k << 6) + 4 * cc);
    acc4(a0, v0);
  }
  a0.x += a1.x + a2.x + a3.x; a0.y += a1.y + a2.y + a3.y;
  a0.z += a1.z + a2.z + a3.z; a0.w += a1.w + a2.w + a3.w;

  *(float4*)(out + (size_t)u * DD + 4 * cc) = a0;
}

// ---------------------------------------------------------------------------
// FC kernel (in-place on d_out): row -> gelu(row*ci) @ W.T + b, 16 rows/wave.
// ---------------------------------------------------------------------------
__global__ __launch_bounds__(256) void gcmc_fc(
    float* __restrict__ out,
    const float* __restrict__ user_ci, const float* __restrict__ movie_ci,
    const float* __restrict__ ufc_w, const float* __restrict__ ufc_b,
    const float* __restrict__ ifc_w, const float* __restrict__ ifc_b)
{
  const int wt   = blockIdx.x * 4 + (threadIdx.x >> 6);
  const int lane = threadIdx.x & 63;
  const int c    = lane & 15;
  const int kr   = lane >> 4;
  const bool isU = wt < (NU / 16);
  float* base        = isU ? out : out + (size_t)NU * DD;
  const float* ci    = isU ? user_ci : movie_ci;
  const float* W     = isU ? ufc_w : ifc_w;
  const float* bias  = isU ? ufc_b : ifc_b;
  const int row0 = (isU ? wt : wt - (NU / 16)) * 16;

  bf16x8 B[4][2];
#pragma unroll
  for (int t = 0; t < 4; ++t)
#pragma unroll
    for (int s = 0; s < 2; ++s)
      B[t][s] = cvt8(W + (size_t)(4 * c + t) * DD + s * 32 + kr * 8);

  const float civ = ci[row0 + c];
  const float* arow = base + (size_t)(row0 + c) * DD + kr * 8;

  bf16x8 A0, A1;
  {
    const float4 a = *(const float4*)arow;
    const float4 b = *(const float4*)(arow + 4);
    const float4 a2 = *(const float4*)(arow + 32);
    const float4 b2 = *(const float4*)(arow + 36);
    A0[0] = f2bf(gelu(a.x * civ));  A0[1] = f2bf(gelu(a.y * civ));
    A0[2] = f2bf(gelu(a.z * civ));  A0[3] = f2bf(gelu(a.w * civ));
    A0[4] = f2bf(gelu(b.x * civ));  A0[5] = f2bf(gelu(b.y * civ));
    A0[6] = f2bf(gelu(b.z * civ));  A0[7] = f2bf(gelu(b.w * civ));
    A1[0] = f2bf(gelu(a2.x * civ)); A1[1] = f2bf(gelu(a2.y * civ));
    A1[2] = f2bf(gelu(a2.z * civ)); A1[3] = f2bf(gelu(a2.w * civ));
    A1[4] = f2bf(gelu(b2.x * civ)); A1[5] = f2bf(gelu(b2.y * civ));
    A1[6] = f2bf(gelu(b2.z * civ)); A1[7] = f2bf(gelu(b2.w * civ));
  }

  f32x4 z4 = {0.f, 0.f, 0.f, 0.f};
  f32x4 C[4];
#pragma unroll
  for (int t = 0; t < 4; ++t) {
    C[t] = z4;
    C[t] = __builtin_amdgcn_mfma_f32_16x16x32_bf16(A0, B[t][0], C[t], 0, 0, 0);
    C[t] = __builtin_amdgcn_mfma_f32_16x16x32_bf16(A1, B[t][1], C[t], 0, 0, 0);
  }

  const float4 b4 = *(const float4*)(bias + 4 * c);
#pragma unroll
  for (int q = 0; q < 4; ++q) {
    const int row = row0 + kr * 4 + q;
    float4 o;
    o.x = C[0][q] + b4.x; o.y = C[1][q] + b4.y;
    o.z = C[2][q] + b4.z; o.w = C[3][q] + b4.w;
    *(float4*)(base + (size_t)row * DD + 4 * c) = o;
  }
}

extern "C" void kernel_launch(void* const* d_in, const int* in_sizes, int n_in,
                              void* d_out, int out_size, void* d_ws, size_t ws_size,
                              hipStream_t stream) {
  const int*   edges_u  = (const int*)  d_in[0];
  const int*   edges_m  = (const int*)  d_in[1];
  const float* rfeat    = (const float*)d_in[2];
  const float* W_user   = (const float*)d_in[3];
  const float* W_movie  = (const float*)d_in[4];
  const float* ps_u     = (const float*)d_in[5];
  const float* rs_u     = (const float*)d_in[6];
  const float* rw_u     = (const float*)d_in[7];
  const float* ps_m     = (const float*)d_in[8];
  const float* rs_m     = (const float*)d_in[9];
  const float* rw_m     = (const float*)d_in[10];
  const float* user_cj  = (const float*)d_in[11];
  const float* user_ci  = (const float*)d_in[12];
  const float* movie_cj = (const float*)d_in[13];
  const float* movie_ci = (const float*)d_in[14];
  const float* ufc_w    = (const float*)d_in[15];
  const float* ufc_b    = (const float*)d_in[16];
  const float* ifc_w    = (const float*)d_in[17];
  const float* ifc_b    = (const float*)d_in[18];

  float* out = (float*)d_out;

  // ---- workspace layout ----
  char* ws = (char*)d_ws;
  size_t o = 0;
  auto alloc = [&](size_t bytes) { char* p = ws + o; o += (bytes + 255) & ~(size_t)255; return p; };
  int*   cnt    = (int*)  alloc(sizeof(int) * NNODE);
  int*   off    = (int*)  alloc(sizeof(int) * (NNODE + 1));
  int*   rank_m = (int*)  alloc(sizeof(int) * NE);
  int*   rank_u = (int*)  alloc(sizeof(int) * NE);
  short* msg    = (short*)alloc(sizeof(short) * (size_t)2 * NE * DD);   // 512 MB
  (void)ws_size;

  hipMemsetAsync(cnt, 0, sizeof(int) * NNODE, stream);
  rank0_k<<<(NE / 4 + 255) / 256, 256, 0, stream>>>(edges_u, edges_m, cnt, rank_m, rank_u);
  scanoff_k<<<1, 1024, 0, stream>>>(cnt, off);

  // one dispatch per relation for profiler visibility
  for (int r = 0; r < RR; ++r) {
    gcmc_main_sorted<<<(EE / 16 + 31) / 32, 256, 0, stream>>>(
        r, edges_u, edges_m, rfeat, W_user, W_movie,
        ps_u, rs_u, rw_u, ps_m, rs_m, rw_m,
        user_cj, movie_cj, rank_m, rank_u, off, msg);
  }

  gather_m_k<<<NM / 4, 256, 0, stream>>>(off, msg, out);
  gather_u_k<<<NU / 16, 256, 0, stream>>>(off, msg, out);

  gcmc_fc<<<(NNODE / 16) / 4, 256, 0, stream>>>(out, user_ci, movie_ci,
                                                ufc_w, ufc_b, ifc_w, ifc_b);
}

// Round 5
// 929.110 us; speedup vs baseline: 1.2326x; 1.0883x over previous
//
#include <hip/hip_runtime.h>
#include <hip/hip_bf16.h>

#define NU 100000
#define NM 20000
#define DD 64
#define RR 5
#define EE 400000
#define NE (RR * EE)            // 2,000,000 edges per direction
#define NNODE (NM + NU)         // 120,000 destination bins (movies first)
#define NTILE (EE / 16)         // 25,000 16-edge tiles per relation

typedef __attribute__((ext_vector_type(8))) short bf16x8;
typedef __attribute__((ext_vector_type(8))) short s16x8;
typedef __attribute__((ext_vector_type(4))) float f32x4;

static __device__ __forceinline__ short f2bf(float f) {
  return __builtin_bit_cast(short, __float2bfloat16(f));
}
static __device__ __forceinline__ float bf2f(short s) {
  return __builtin_bit_cast(float, ((unsigned)(unsigned short)s) << 16);
}

static __device__ __forceinline__ bf16x8 pack8(const float4 a, const float4 b) {
  bf16x8 o;
  o[0] = f2bf(a.x); o[1] = f2bf(a.y); o[2] = f2bf(a.z); o[3] = f2bf(a.w);
  o[4] = f2bf(b.x); o[5] = f2bf(b.y); o[6] = f2bf(b.z); o[7] = f2bf(b.w);
  return o;
}
static __device__ __forceinline__ bf16x8 cvt8(const float* __restrict__ p) {
  return pack8(*(const float4*)p, *(const float4*)(p + 4));
}

static __device__ __forceinline__ float sigm(float x) { return 1.f / (1.f + __expf(-x)); }
static __device__ __forceinline__ float gelu(float x) {
  return 0.5f * x * (1.f + erff(x * 0.70710678118654752f));
}

// ---------------------------------------------------------------------------
// rank0: ONE atomic pass. cnt (zeroed) -> per-edge rank within destination,
// and cnt ends up holding the per-node degree (input to scanoff).
// ---------------------------------------------------------------------------
__global__ __launch_bounds__(256) void rank0_k(const int* __restrict__ eu,
                                               const int* __restrict__ em,
                                               int* __restrict__ cnt,
                                               int* __restrict__ rank_m,
                                               int* __restrict__ rank_u) {
  const int i = (blockIdx.x * 256 + threadIdx.x) * 4;
  if (i < NE) {
    const int4 a = *(const int4*)(em + i);
    const int4 b = *(const int4*)(eu + i);
    int4 rm, ru;
    rm.x = atomicAdd(&cnt[a.x], 1);
    rm.y = atomicAdd(&cnt[a.y], 1);
    rm.z = atomicAdd(&cnt[a.z], 1);
    rm.w = atomicAdd(&cnt[a.w], 1);
    ru.x = atomicAdd(&cnt[NM + b.x], 1);
    ru.y = atomicAdd(&cnt[NM + b.y], 1);
    ru.z = atomicAdd(&cnt[NM + b.z], 1);
    ru.w = atomicAdd(&cnt[NM + b.w], 1);
    *(int4*)(rank_m + i) = rm;
    *(int4*)(rank_u + i) = ru;
  }
}

__global__ __launch_bounds__(1024) void scanoff_k(const int* __restrict__ cnt,
                                                  int* __restrict__ off) {
  __shared__ int sums[1024];
  const int t = threadIdx.x;
  const int ch = (NNODE + 1023) >> 10;    // 118
  const int b0 = t * ch;
  int s = 0;
  for (int i = 0; i < ch; ++i) { int idx = b0 + i; if (idx < NNODE) s += cnt[idx]; }
  sums[t] = s;
  __syncthreads();
  for (int d = 1; d < 1024; d <<= 1) {
    int x = (t >= d) ? sums[t - d] : 0;
    __syncthreads();
    sums[t] += x;
    __syncthreads();
  }
  int run = (t > 0) ? sums[t - 1] : 0;
  for (int i = 0; i < ch; ++i) {
    int idx = b0 + i;
    if (idx < NNODE) { off[idx] = run; run += cnt[idx]; }
  }
  if (t == 1023) off[NNODE] = sums[1023];
}

// ---------------------------------------------------------------------------
// Main fused MFMA kernel, software-pipelined 1 tile deep.
// Per 16-edge tile: both directions' messages via one MFMA pass, stored (bf16)
// at slot = off[dst] + rank.  Column permutation: tile t, col c -> dim 4c+t.
// ---------------------------------------------------------------------------
__global__ __launch_bounds__(256) void gcmc_main(
    const int* __restrict__ edges_u, const int* __restrict__ edges_m,
    const float* __restrict__ rfeat,
    const float* __restrict__ W_user, const float* __restrict__ W_movie,
    const float* __restrict__ ps_u, const float* __restrict__ rs_u, const float* __restrict__ rw_u,
    const float* __restrict__ ps_m, const float* __restrict__ rs_m, const float* __restrict__ rw_m,
    const float* __restrict__ user_cj, const float* __restrict__ movie_cj,
    const int* __restrict__ rank_m, const int* __restrict__ rank_u,
    const int* __restrict__ off,
    short* __restrict__ msg)
{
  const int r    = blockIdx.y;
  const int lane = threadIdx.x & 63;
  const int wid  = threadIdx.x >> 6;
  const int c    = lane & 15;
  const int kr   = lane >> 4;
  const int wtile = blockIdx.x * 4 + wid;
  if (wtile >= NTILE / 8) return;        // 25000 % 8 == 0: all-or-nothing waves
  const int wt8 = wtile * 8;

  // ---- B fragments in registers (bf16), loaded once per wave ----
  bf16x8 Bu[4][2], Bm[4][2], Bs[2];
#pragma unroll
  for (int t = 0; t < 4; ++t) {
#pragma unroll
    for (int s = 0; s < 2; ++s) {
      Bu[t][s] = cvt8(rw_u + ((size_t)r * DD + (4 * c + t)) * DD + s * 32 + kr * 8);
      Bm[t][s] = cvt8(rw_m + ((size_t)r * DD + (4 * c + t)) * DD + s * 32 + kr * 8);
    }
  }
#pragma unroll
  for (int s = 0; s < 2; ++s) {
    if (c < 4) {
      const float* v = (c == 0 ? rs_u : c == 1 ? ps_u : c == 2 ? rs_m : ps_m)
                       + r * DD + s * 32 + kr * 8;
      Bs[s] = cvt8(v);
    } else {
      bf16x8 z = {0, 0, 0, 0, 0, 0, 0, 0};
      Bs[s] = z;
    }
  }

  // ---- double-buffered raw loads ----
  float4 fA[2][4];
  int4   iE[2][4];   // [eu, em, rank_m, rank_u]

  auto LOAD = [&](int tile, int b) {
    const int e0 = tile * 16;
    const float* arow = rfeat + ((size_t)r * EE + e0 + c) * DD + kr * 8;
    fA[b][0] = *(const float4*)arow;
    fA[b][1] = *(const float4*)(arow + 4);
    fA[b][2] = *(const float4*)(arow + 32);
    fA[b][3] = *(const float4*)(arow + 36);
    const int eb = r * EE + e0 + kr * 4;
    iE[b][0] = *(const int4*)(edges_u + eb);
    iE[b][1] = *(const int4*)(edges_m + eb);
    iE[b][2] = *(const int4*)(rank_m + eb);
    iE[b][3] = *(const int4*)(rank_u + eb);
  };

  auto PROCESS = [&](int b) {
    const int4 eu4 = iE[b][0], em4 = iE[b][1], rm4 = iE[b][2], ru4 = iE[b][3];
    const int eus[4] = {eu4.x, eu4.y, eu4.z, eu4.w};
    const int ems[4] = {em4.x, em4.y, em4.z, em4.w};
    const int rms[4] = {rm4.x, rm4.y, rm4.z, rm4.w};
    const int rus[4] = {ru4.x, ru4.y, ru4.z, ru4.w};

    // dependent gathers, all issued up-front; latency overlapped by cvt+MFMA
    int slm[4], slu[4];
    float cju[4], cjm[4];
    float4 hu[4], hm[4];
#pragma unroll
    for (int q = 0; q < 4; ++q) {
      slm[q] = off[ems[q]] + rms[q];
      slu[q] = off[NM + eus[q]] + rus[q];
      cju[q] = user_cj[eus[q]];
      cjm[q] = movie_cj[ems[q]];
      hu[q]  = *(const float4*)(W_user  + ((size_t)r * NU + eus[q]) * DD + 4 * c);
      hm[q]  = *(const float4*)(W_movie + ((size_t)r * NM + ems[q]) * DD + 4 * c);
    }

    const bf16x8 A0 = pack8(fA[b][0], fA[b][1]);
    const bf16x8 A1 = pack8(fA[b][2], fA[b][3]);

    f32x4 z4 = {0.f, 0.f, 0.f, 0.f};
    f32x4 Cu[4], Cm[4], Cs;
#pragma unroll
    for (int t = 0; t < 4; ++t) { Cu[t] = z4; Cm[t] = z4; }
    Cs = z4;
#pragma unroll
    for (int t = 0; t < 4; ++t) {
      Cu[t] = __builtin_amdgcn_mfma_f32_16x16x32_bf16(A0, Bu[t][0], Cu[t], 0, 0, 0);
      Cu[t] = __builtin_amdgcn_mfma_f32_16x16x32_bf16(A1, Bu[t][1], Cu[t], 0, 0, 0);
      Cm[t] = __builtin_amdgcn_mfma_f32_16x16x32_bf16(A0, Bm[t][0], Cm[t], 0, 0, 0);
      Cm[t] = __builtin_amdgcn_mfma_f32_16x16x32_bf16(A1, Bm[t][1], Cm[t], 0, 0, 0);
    }
    Cs = __builtin_amdgcn_mfma_f32_16x16x32_bf16(A0, Bs[0], Cs, 0, 0, 0);
    Cs = __builtin_amdgcn_mfma_f32_16x16x32_bf16(A1, Bs[1], Cs, 0, 0, 0);

#pragma unroll
    for (int q = 0; q < 4; ++q) {
      const int src = (lane & 48);
      const float su = __shfl(Cs[q], src);
      const float pu = __shfl(Cs[q], src | 1);
      const float sm = __shfl(Cs[q], src | 2);
      const float pm = __shfl(Cs[q], src | 3);
      const float sgu = sigm(su), pau = sigm(pu);
      const float sgm_ = sigm(sm), pam = sigm(pm);

      short4 vm, vu;
      vm.x = f2bf((hu[q].x * pau + Cu[0][q] * sgu) * cju[q]);
      vm.y = f2bf((hu[q].y * pau + Cu[1][q] * sgu) * cju[q]);
      vm.z = f2bf((hu[q].z * pau + Cu[2][q] * sgu) * cju[q]);
      vm.w = f2bf((hu[q].w * pau + Cu[3][q] * sgu) * cju[q]);
      vu.x = f2bf((hm[q].x * pam + Cm[0][q] * sgm_) * cjm[q]);
      vu.y = f2bf((hm[q].y * pam + Cm[1][q] * sgm_) * cjm[q]);
      vu.z = f2bf((hm[q].z * pam + Cm[2][q] * sgm_) * cjm[q]);
      vu.w = f2bf((hm[q].w * pam + Cm[3][q] * sgm_) * cjm[q]);

      *(short4*)(msg + ((size_t)slm[q] << 6) + 4 * c) = vm;
      *(short4*)(msg + ((size_t)slu[q] << 6) + 4 * c) = vu;
    }
  };

  LOAD(wt8, 0);
#pragma unroll 1
  for (int tt = 0; tt < 8; tt += 2) {
    LOAD(wt8 + tt + 1, 1);        // next tile's raw loads in flight
    PROCESS(0);
    if (tt < 6) LOAD(wt8 + tt + 2, 0);
    PROCESS(1);
  }
}

// ---------------------------------------------------------------------------
// Gather-reduce, movies: one wave per movie (avg deg 100).
// 8 lanes per row (16 B/lane b128 loads), 8 rows in flight, 2-deep unrolled.
// ---------------------------------------------------------------------------
__global__ __launch_bounds__(256) void gather_m_k(const int* __restrict__ off,
                                                  const short* __restrict__ msg,
                                                  float* __restrict__ out)
{
  const int w    = blockIdx.x * 4 + (threadIdx.x >> 6);   // movie id
  const int lane = threadIdx.x & 63;
  const int sub  = lane >> 3;    // row group 0..7
  const int c8   = lane & 7;     // 16-byte chunk

  const int s0 = off[w];
  const int e1 = off[w + 1];

  float a0[8] = {0,0,0,0,0,0,0,0};
  float a1[8] = {0,0,0,0,0,0,0,0};
  int k = s0 + sub;
  for (; k + 8 < e1; k += 16) {
    const s16x8 v0 = *(const s16x8*)(msg + ((size_t)k << 6) + 8 * c8);
    const s16x8 v1 = *(const s16x8*)(msg + ((size_t)(k + 8) << 6) + 8 * c8);
#pragma unroll
    for (int j = 0; j < 8; ++j) { a0[j] += bf2f(v0[j]); a1[j] += bf2f(v1[j]); }
  }
  if (k < e1) {
    const s16x8 v0 = *(const s16x8*)(msg + ((size_t)k << 6) + 8 * c8);
#pragma unroll
    for (int j = 0; j < 8; ++j) a0[j] += bf2f(v0[j]);
  }
#pragma unroll
  for (int j = 0; j < 8; ++j) {
    a0[j] += a1[j];
    a0[j] += __shfl_xor(a0[j], 8);
    a0[j] += __shfl_xor(a0[j], 16);
    a0[j] += __shfl_xor(a0[j], 32);
  }
  if (sub == 0) {
    float* dst = out + (size_t)NU * DD + (size_t)w * DD + 8 * c8;
    float4 o0 = {a0[0], a0[1], a0[2], a0[3]};
    float4 o1 = {a0[4], a0[5], a0[6], a0[7]};
    *(float4*)dst = o0;
    *(float4*)(dst + 4) = o1;
  }
}

// ---------------------------------------------------------------------------
// Gather-reduce, users: 8 lanes per user (avg deg 20), 32 users/block,
// 16 B/lane b128 loads, 4-deep unrolled.
// ---------------------------------------------------------------------------
__global__ __launch_bounds__(256) void gather_u_k(const int* __restrict__ off,
                                                  const short* __restrict__ msg,
                                                  float* __restrict__ out)
{
  const int u  = blockIdx.x * 32 + (threadIdx.x >> 3);    // user id
  const int c8 = threadIdx.x & 7;

  const int s0 = off[NM + u];
  const int e1 = off[NM + u + 1];

  float a0[8] = {0,0,0,0,0,0,0,0};
  float a1[8] = {0,0,0,0,0,0,0,0};
  float a2[8] = {0,0,0,0,0,0,0,0};
  float a3[8] = {0,0,0,0,0,0,0,0};
  int k = s0;
  for (; k + 3 < e1; k += 4) {
    const s16x8 v0 = *(const s16x8*)(msg + ((size_t)k << 6) + 8 * c8);
    const s16x8 v1 = *(const s16x8*)(msg + ((size_t)(k + 1) << 6) + 8 * c8);
    const s16x8 v2 = *(const s16x8*)(msg + ((size_t)(k + 2) << 6) + 8 * c8);
    const s16x8 v3 = *(const s16x8*)(msg + ((size_t)(k + 3) << 6) + 8 * c8);
#pragma unroll
    for (int j = 0; j < 8; ++j) {
      a0[j] += bf2f(v0[j]); a1[j] += bf2f(v1[j]);
      a2[j] += bf2f(v2[j]); a3[j] += bf2f(v3[j]);
    }
  }
  for (; k < e1; ++k) {
    const s16x8 v0 = *(const s16x8*)(msg + ((size_t)k << 6) + 8 * c8);
#pragma unroll
    for (int j = 0; j < 8; ++j) a0[j] += bf2f(v0[j]);
  }
  float* dst = out + (size_t)u * DD + 8 * c8;
  float4 o0, o1;
  o0.x = a0[0] + a1[0] + a2[0] + a3[0];
  o0.y = a0[1] + a1[1] + a2[1] + a3[1];
  o0.z = a0[2] + a1[2] + a2[2] + a3[2];
  o0.w = a0[3] + a1[3] + a2[3] + a3[3];
  o1.x = a0[4] + a1[4] + a2[4] + a3[4];
  o1.y = a0[5] + a1[5] + a2[5] + a3[5];
  o1.z = a0[6] + a1[6] + a2[6] + a3[6];
  o1.w = a0[7] + a1[7] + a2[7] + a3[7];
  *(float4*)dst = o0;
  *(float4*)(dst + 4) = o1;
}

// ---------------------------------------------------------------------------
// FC kernel (in-place on d_out): row -> gelu(row*ci) @ W.T + b, 16 rows/wave.
// ---------------------------------------------------------------------------
__global__ __launch_bounds__(256) void gcmc_fc(
    float* __restrict__ out,
    const float* __restrict__ user_ci, const float* __restrict__ movie_ci,
    const float* __restrict__ ufc_w, const float* __restrict__ ufc_b,
    const float* __restrict__ ifc_w, const float* __restrict__ ifc_b)
{
  const int wt   = blockIdx.x * 4 + (threadIdx.x >> 6);
  const int lane = threadIdx.x & 63;
  const int c    = lane & 15;
  const int kr   = lane >> 4;
  const bool isU = wt < (NU / 16);
  float* base        = isU ? out : out + (size_t)NU * DD;
  const float* ci    = isU ? user_ci : movie_ci;
  const float* W     = isU ? ufc_w : ifc_w;
  const float* bias  = isU ? ufc_b : ifc_b;
  const int row0 = (isU ? wt : wt - (NU / 16)) * 16;

  bf16x8 B[4][2];
#pragma unroll
  for (int t = 0; t < 4; ++t)
#pragma unroll
    for (int s = 0; s < 2; ++s)
      B[t][s] = cvt8(W + (size_t)(4 * c + t) * DD + s * 32 + kr * 8);

  const float civ = ci[row0 + c];
  const float* arow = base + (size_t)(row0 + c) * DD + kr * 8;

  bf16x8 A0, A1;
  {
    const float4 a = *(const float4*)arow;
    const float4 b = *(const float4*)(arow + 4);
    const float4 a2 = *(const float4*)(arow + 32);
    const float4 b2 = *(const float4*)(arow + 36);
    A0[0] = f2bf(gelu(a.x * civ));  A0[1] = f2bf(gelu(a.y * civ));
    A0[2] = f2bf(gelu(a.z * civ));  A0[3] = f2bf(gelu(a.w * civ));
    A0[4] = f2bf(gelu(b.x * civ));  A0[5] = f2bf(gelu(b.y * civ));
    A0[6] = f2bf(gelu(b.z * civ));  A0[7] = f2bf(gelu(b.w * civ));
    A1[0] = f2bf(gelu(a2.x * civ)); A1[1] = f2bf(gelu(a2.y * civ));
    A1[2] = f2bf(gelu(a2.z * civ)); A1[3] = f2bf(gelu(a2.w * civ));
    A1[4] = f2bf(gelu(b2.x * civ)); A1[5] = f2bf(gelu(b2.y * civ));
    A1[6] = f2bf(gelu(b2.z * civ)); A1[7] = f2bf(gelu(b2.w * civ));
  }

  f32x4 z4 = {0.f, 0.f, 0.f, 0.f};
  f32x4 C[4];
#pragma unroll
  for (int t = 0; t < 4; ++t) {
    C[t] = z4;
    C[t] = __builtin_amdgcn_mfma_f32_16x16x32_bf16(A0, B[t][0], C[t], 0, 0, 0);
    C[t] = __builtin_amdgcn_mfma_f32_16x16x32_bf16(A1, B[t][1], C[t], 0, 0, 0);
  }

  const float4 b4 = *(const float4*)(bias + 4 * c);
#pragma unroll
  for (int q = 0; q < 4; ++q) {
    const int row = row0 + kr * 4 + q;
    float4 o;
    o.x = C[0][q] + b4.x; o.y = C[1][q] + b4.y;
    o.z = C[2][q] + b4.z; o.w = C[3][q] + b4.w;
    *(float4*)(base + (size_t)row * DD + 4 * c) = o;
  }
}

extern "C" void kernel_launch(void* const* d_in, const int* in_sizes, int n_in,
                              void* d_out, int out_size, void* d_ws, size_t ws_size,
                              hipStream_t stream) {
  const int*   edges_u  = (const int*)  d_in[0];
  const int*   edges_m  = (const int*)  d_in[1];
  const float* rfeat    = (const float*)d_in[2];
  const float* W_user   = (const float*)d_in[3];
  const float* W_movie  = (const float*)d_in[4];
  const float* ps_u     = (const float*)d_in[5];
  const float* rs_u     = (const float*)d_in[6];
  const float* rw_u     = (const float*)d_in[7];
  const float* ps_m     = (const float*)d_in[8];
  const float* rs_m     = (const float*)d_in[9];
  const float* rw_m     = (const float*)d_in[10];
  const float* user_cj  = (const float*)d_in[11];
  const float* user_ci  = (const float*)d_in[12];
  const float* movie_cj = (const float*)d_in[13];
  const float* movie_ci = (const float*)d_in[14];
  const float* ufc_w    = (const float*)d_in[15];
  const float* ufc_b    = (const float*)d_in[16];
  const float* ifc_w    = (const float*)d_in[17];
  const float* ifc_b    = (const float*)d_in[18];

  float* out = (float*)d_out;

  // ---- workspace layout ----
  char* ws = (char*)d_ws;
  size_t o = 0;
  auto alloc = [&](size_t bytes) { char* p = ws + o; o += (bytes + 255) & ~(size_t)255; return p; };
  int*   cnt    = (int*)  alloc(sizeof(int) * NNODE);
  int*   off    = (int*)  alloc(sizeof(int) * (NNODE + 1));
  int*   rank_m = (int*)  alloc(sizeof(int) * NE);
  int*   rank_u = (int*)  alloc(sizeof(int) * NE);
  short* msg    = (short*)alloc(sizeof(short) * (size_t)2 * NE * DD);   // 512 MB
  (void)ws_size;

  hipMemsetAsync(cnt, 0, sizeof(int) * NNODE, stream);
  rank0_k<<<(NE / 4 + 255) / 256, 256, 0, stream>>>(edges_u, edges_m, cnt, rank_m, rank_u);
  scanoff_k<<<1, 1024, 0, stream>>>(cnt, off);

  dim3 g1((NTILE / 8 + 3) / 4, RR);   // (782, 5)
  gcmc_main<<<g1, 256, 0, stream>>>(edges_u, edges_m, rfeat, W_user, W_movie,
                                    ps_u, rs_u, rw_u, ps_m, rs_m, rw_m,
                                    user_cj, movie_cj, rank_m, rank_u, off, msg);

  gather_m_k<<<NM / 4, 256, 0, stream>>>(off, msg, out);
  gather_u_k<<<NU / 32, 256, 0, stream>>>(off, msg, out);

  gcmc_fc<<<(NNODE / 16) / 4, 256, 0, stream>>>(out, user_ci, movie_ci,
                                                ufc_w, ufc_b, ifc_w, ifc_b);
}